// Round 6
// baseline (936.377 us; speedup 1.0000x reference)
//
#include <hip/hip_runtime.h>

#define N_NODES   100000
#define N_EDGES   1600000
#define WALK_LEN  16
#define OUT_DIM   8
#define N_PROBES  32

#define SCAN_BLK  256
#define NBLK      ((N_NODES + SCAN_BLK - 1) / SCAN_BLK)   // 391

// ---- LDS byte-counter build parameters ----
#define HB        128                      // histogram blocks per array (row/col)
#define SLICE     (N_EDGES / HB)           // 12500 edges per block (exact)
#define NWORDS    (N_NODES / 4)            // 25000 packed uints = 100 KB LDS
#define RB        ((NWORDS + 255) / 256)   // reduce blocks per half

// ---- adjacency padding: every list rounded up to multiple of 16 (burst) ----
#define BURST     16
#define DUMMY     N_NODES                  // dummy source row (always zero)
#define CSC_CAP   (N_EDGES + (BURST - 1) * N_NODES)   // 3.1M padded entries

typedef _Float16 half4 __attribute__((ext_vector_type(4)));
typedef float float2v __attribute__((ext_vector_type(2)));

__device__ __forceinline__ int pad_burst(int x) { return (x + BURST - 1) & ~(BURST - 1); }

// ---------------- fused per-block byte-packed histograms: row -> partialR, col -> partialC ----
// 256 blocks total (1 per CU): blocks [0,HB) histogram row, [HB,2HB) histogram col.
__global__ void hist2_kernel(const int* __restrict__ row, const int* __restrict__ col,
                             unsigned char* __restrict__ partialR,
                             unsigned char* __restrict__ partialC) {
    __shared__ unsigned int cnt[NWORDS];
    int blk = blockIdx.x;
    const int* arr = (blk < HB) ? row : col;
    unsigned char* partial = (blk < HB) ? partialR : partialC;
    int b = (blk < HB) ? blk : blk - HB;
    int t = threadIdx.x;                   // 1024 threads
    for (int i = t; i < NWORDS; i += 1024) cnt[i] = 0;
    __syncthreads();
    const int* a = arr + b * SLICE;
    for (int i = t; i < SLICE; i += 1024) {
        int v = a[i];
        atomicAdd(&cnt[v >> 2], 1u << ((v & 3) * 8));
    }
    __syncthreads();
    unsigned int* dst = (unsigned int*)(partial + (size_t)b * N_NODES);
    for (int i = t; i < NWORDS; i += 1024) dst[i] = cnt[i];
}

// ---------------- fused reduces: half A: outdeg->inv; half B: indeg + in-place prefix ----
__global__ void reduce2_kernel(const unsigned char* __restrict__ partialR,
                               float* __restrict__ inv_outdeg,
                               unsigned char* __restrict__ partialC,
                               int* __restrict__ indeg) {
    int blk = blockIdx.x;
    if (blk < RB) {
        int q = blk * 256 + threadIdx.x;
        if (q >= NWORDS) return;
        int s0 = 0, s1 = 0, s2 = 0, s3 = 0;
        for (int b = 0; b < HB; b++) {
            unsigned int w = *(const unsigned int*)(partialR + (size_t)b * N_NODES + q * 4);
            s0 += w & 0xFF; s1 += (w >> 8) & 0xFF; s2 += (w >> 16) & 0xFF; s3 += (w >> 24) & 0xFF;
        }
        int n = q * 4;
        inv_outdeg[n + 0] = 1.0f / (float)(s0 > 0 ? s0 : 1);
        inv_outdeg[n + 1] = 1.0f / (float)(s1 > 0 ? s1 : 1);
        inv_outdeg[n + 2] = 1.0f / (float)(s2 > 0 ? s2 : 1);
        inv_outdeg[n + 3] = 1.0f / (float)(s3 > 0 ? s3 : 1);
    } else {
        int q = (blk - RB) * 256 + threadIdx.x;
        if (q >= NWORDS) return;
        unsigned int r0 = 0, r1 = 0, r2 = 0, r3 = 0;     // running prefixes (fit in a byte)
        for (int b = 0; b < HB; b++) {
            unsigned int* p = (unsigned int*)(partialC + (size_t)b * N_NODES + q * 4);
            unsigned int w = *p;
            *p = (r0 & 0xFF) | ((r1 & 0xFF) << 8) | ((r2 & 0xFF) << 16) | ((r3 & 0xFF) << 24);
            r0 += w & 0xFF; r1 += (w >> 8) & 0xFF; r2 += (w >> 16) & 0xFF; r3 += (w >> 24) & 0xFF;
        }
        int n = q * 4;
        indeg[n + 0] = (int)r0;
        indeg[n + 1] = (int)r1;
        indeg[n + 2] = (int)r2;
        indeg[n + 3] = (int)r3;
    }
}

// ---------------- prefix scan of PADDED indeg -> offs (exclusive) ----------------
__global__ void scan1_kernel(const int* __restrict__ indeg, int* __restrict__ bsum) {
    __shared__ int s[SCAN_BLK];
    int i = blockIdx.x * SCAN_BLK + threadIdx.x;
    s[threadIdx.x] = (i < N_NODES) ? pad_burst(indeg[i]) : 0;
    __syncthreads();
    for (int o = SCAN_BLK / 2; o > 0; o >>= 1) {
        if (threadIdx.x < o) s[threadIdx.x] += s[threadIdx.x + o];
        __syncthreads();
    }
    if (threadIdx.x == 0) bsum[blockIdx.x] = s[0];
}

__global__ void scan2_kernel(int* __restrict__ bsum) {   // single block of 512
    __shared__ int s[512];
    int t = threadIdx.x;
    s[t] = (t < NBLK) ? bsum[t] : 0;
    __syncthreads();
    for (int o = 1; o < 512; o <<= 1) {
        int v = (t >= o) ? s[t - o] : 0;
        __syncthreads();
        s[t] += v;
        __syncthreads();
    }
    if (t < NBLK) bsum[t] = (t == 0) ? 0 : s[t - 1];     // exclusive
}

__global__ void scan3_kernel(const int* __restrict__ indeg, const int* __restrict__ bsum,
                             int* __restrict__ offs) {
    __shared__ int s[SCAN_BLK];
    int t = threadIdx.x;
    int i = blockIdx.x * SCAN_BLK + t;
    int v = (i < N_NODES) ? pad_burst(indeg[i]) : 0;
    s[t] = v;
    __syncthreads();
    for (int o = 1; o < SCAN_BLK; o <<= 1) {
        int u = (t >= o) ? s[t - o] : 0;
        __syncthreads();
        s[t] += u;
        __syncthreads();
    }
    if (i < N_NODES) offs[i] = bsum[blockIdx.x] + s[t] - v;   // exclusive
}

// ---------------- fill csc_row with DUMMY (pad slots resolve to zero row) ----------------
__global__ void fill_dummy_kernel(int* __restrict__ csc_row) {
    int i = blockIdx.x * blockDim.x + threadIdx.x;   // [0, CSC_CAP/4)
    if (i >= CSC_CAP / 4) return;
    reinterpret_cast<int4*>(csc_row)[i] = make_int4(DUMMY, DUMMY, DUMMY, DUMMY);
}

// ---------------- CSC fill: LDS byte rank counters seeded with prefix base ----------------
__global__ void place_kernel(const int* __restrict__ row, const int* __restrict__ col,
                             const int* __restrict__ offs,
                             const unsigned char* __restrict__ pbase,
                             int* __restrict__ csc_row) {
    __shared__ unsigned int cnt[NWORDS];
    int b = blockIdx.x;
    int t = threadIdx.x;                   // 1024 threads
    const unsigned int* src = (const unsigned int*)(pbase + (size_t)b * N_NODES);
    for (int i = t; i < NWORDS; i += 1024) cnt[i] = src[i];   // seed with prefix-base bytes
    __syncthreads();
    for (int i = t; i < SLICE; i += 1024) {
        int e = b * SLICE + i;
        int c = col[e];
        int sh = (c & 3) * 8;
        unsigned int old = atomicAdd(&cnt[c >> 2], 1u << sh);
        int pos = (int)((old >> sh) & 0xFF);               // prefix-base + in-block rank
        csc_row[offs[c] + pos] = row[e];
    }
}

// ---------------- fused: s0 = fp16(probes*inv_od), probe-sign pack, dummy-row zero ----------
__global__ void s0pack_kernel(const float* __restrict__ probes, const float* __restrict__ inv_outdeg,
                              _Float16* __restrict__ s0h, unsigned int* __restrict__ pbits,
                              unsigned int* __restrict__ a8, unsigned int* __restrict__ b8) {
    int gid = blockIdx.x * blockDim.x + threadIdx.x;   // [0, N*8)
    if (gid < 16)      reinterpret_cast<unsigned int*>(s0h + (size_t)DUMMY * N_PROBES)[gid] = 0u;
    else if (gid < 24) a8[(size_t)DUMMY * 8 + (gid - 16)] = 0u;
    else if (gid < 32) b8[(size_t)DUMMY * 8 + (gid - 24)] = 0u;
    int n = gid >> 3;
    int j = (gid & 7) << 2;
    float iv = inv_outdeg[n];
    const float4 p = *reinterpret_cast<const float4*>(probes + (size_t)n * N_PROBES + j);
    half4 h;
    h[0] = (_Float16)(p.x * iv); h[1] = (_Float16)(p.y * iv);
    h[2] = (_Float16)(p.z * iv); h[3] = (_Float16)(p.w * iv);
    *reinterpret_cast<half4*>(s0h + (size_t)n * N_PROBES + j) = h;
    unsigned int b4 = (p.x < 0.f ? 1u : 0u) | (p.y < 0.f ? 2u : 0u) |
                      (p.z < 0.f ? 4u : 0u) | (p.w < 0.f ? 8u : 0u);
    unsigned int bits = b4 << j;
    bits |= __shfl_xor(bits, 1, 8);
    bits |= __shfl_xor(bits, 2, 8);
    bits |= __shfl_xor(bits, 4, 8);
    if ((gid & 7) == 0) pbits[n] = bits;
}

// ---------------- fused gather + rescale + Hutchinson diag ----------------
// State rows: 32 probes. IN8=false: fp16 rows (64B, lane reads 8B half4) — step 0 only.
// IN8=true: fp8 e4m3 rows (32B, lane reads 4B dword, HW cvt_pk_f32_fp8 unpack).
// Output always fp8. fp32 accumulation. Padded burst-16 + one-burst-ahead NT index prefetch.
// __launch_bounds__(256,7): cap ~72 VGPR -> 28 waves/CU for max outstanding-miss concurrency
// (L3-latency-bound regime: per-step time ~ misses*latency/concurrency).
template <bool IN8>
__global__ __launch_bounds__(256, 7)
void gather_kernel(const int* __restrict__ offs, const int* __restrict__ indeg,
                   const int* __restrict__ csc_row,
                   const void* __restrict__ s_cur,
                   const unsigned int* __restrict__ pbits,
                   const float* __restrict__ inv_outdeg,
                   unsigned int* __restrict__ s_new, float* __restrict__ diag_row) {
    int gid = blockIdx.x * blockDim.x + threadIdx.x;   // [0, N*8) exact
    int n = gid >> 3;
    int lane = gid & 7;
    int start = offs[n];
    int pcnt  = pad_burst(indeg[n]);                   // multiple of BURST
    float inv = inv_outdeg[n];
    float4 acc = make_float4(0.f, 0.f, 0.f, 0.f);

    const _Float16*     h_base = (const _Float16*)s_cur;
    const unsigned int* q_base = (const unsigned int*)s_cur;

    int r[BURST];
    if (pcnt > 0) {
#pragma unroll
        for (int u = 0; u < BURST; u++)
            r[u] = __builtin_nontemporal_load(&csc_row[start + u]);
    }
    for (int q = 0; q < pcnt; q += BURST) {
        // issue BURST independent state loads (32-bit element indexing)
        half4        vh[BURST];
        unsigned int vq[BURST];
#pragma unroll
        for (int u = 0; u < BURST; u++) {
            if (IN8) vq[u] = q_base[r[u] * 8 + lane];
            else     vh[u] = *reinterpret_cast<const half4*>(h_base + r[u] * N_PROBES + lane * 4);
        }
        // prefetch next burst's indices while state loads are in flight
        int r2[BURST];
        if (q + BURST < pcnt) {
#pragma unroll
            for (int u = 0; u < BURST; u++)
                r2[u] = __builtin_nontemporal_load(&csc_row[start + q + BURST + u]);
        }
#pragma unroll
        for (int u = 0; u < BURST; u++) {
            if (IN8) {
                float2v lo = __builtin_amdgcn_cvt_pk_f32_fp8((int)vq[u], false);
                float2v hi = __builtin_amdgcn_cvt_pk_f32_fp8((int)vq[u], true);
                acc.x += lo[0]; acc.y += lo[1]; acc.z += hi[0]; acc.w += hi[1];
            } else {
                acc.x += (float)vh[u][0]; acc.y += (float)vh[u][1];
                acc.z += (float)vh[u][2]; acc.w += (float)vh[u][3];
            }
        }
#pragma unroll
        for (int u = 0; u < BURST; u++) r[u] = r2[u];
    }

    // acc = P_k[n] fragment (fp32). Write pre-scaled fp8 row for next step.
    int pk = 0;
    pk = __builtin_amdgcn_cvt_pk_fp8_f32(acc.x * inv, acc.y * inv, pk, false);
    pk = __builtin_amdgcn_cvt_pk_fp8_f32(acc.z * inv, acc.w * inv, pk, true);
    s_new[n * 8 + lane] = (unsigned int)pk;

    // Hutchinson dot via packed probe signs (probes are exactly ±1)
    unsigned int bits = pbits[n] >> (lane << 2);
    float d0 = (bits & 1u) ? -acc.x : acc.x;
    float d1 = (bits & 2u) ? -acc.y : acc.y;
    float d2 = (bits & 4u) ? -acc.z : acc.z;
    float d3 = (bits & 8u) ? -acc.w : acc.w;
    float dot = d0 + d1 + d2 + d3;
    dot += __shfl_xor(dot, 4, 8);
    dot += __shfl_xor(dot, 2, 8);
    dot += __shfl_xor(dot, 1, 8);
    if (lane == 0) diag_row[n] = dot * (1.0f / (float)N_PROBES);
}

// ---------------- out[n] = diags[n,:] @ W^T + b ----------------
__global__ void out_kernel(const float* __restrict__ diags, const float* __restrict__ W,
                           const float* __restrict__ b, float* __restrict__ out) {
    int n = blockIdx.x * blockDim.x + threadIdx.x;
    if (n >= N_NODES) return;
    float d[WALK_LEN];
#pragma unroll
    for (int k = 0; k < WALK_LEN; k++) d[k] = diags[(size_t)k * N_NODES + n];
    float o[OUT_DIM];
#pragma unroll
    for (int j = 0; j < OUT_DIM; j++) {
        float acc = b[j];
#pragma unroll
        for (int k = 0; k < WALK_LEN; k++) acc += d[k] * W[j * WALK_LEN + k];
        o[j] = acc;
    }
    float4* outp = reinterpret_cast<float4*>(out + (size_t)n * OUT_DIM);
    outp[0] = make_float4(o[0], o[1], o[2], o[3]);
    outp[1] = make_float4(o[4], o[5], o[6], o[7]);
}

extern "C" void kernel_launch(void* const* d_in, const int* in_sizes, int n_in,
                              void* d_out, int out_size, void* d_ws, size_t ws_size,
                              hipStream_t stream) {
    const int*   edge_index = (const int*)d_in[0];
    const int*   row    = edge_index;
    const int*   col    = edge_index + N_EDGES;
    const float* probes = (const float*)d_in[2];
    const float* W      = (const float*)d_in[3];
    const float* b      = (const float*)d_in[4];
    float*       out    = (float*)d_out;

    // workspace carve-up (256B aligned)
    char* ws = (char*)d_ws;
    size_t off = 0;
    auto carve = [&](size_t bytes) -> void* {
        void* p = ws + off;
        off += (bytes + 255) & ~(size_t)255;
        return p;
    };
    int*           indeg    = (int*)          carve((size_t)N_NODES * 4);              // 400 KB
    int*           offs     = (int*)          carve((size_t)N_NODES * 4);              // 400 KB
    float*         inv_od   = (float*)        carve((size_t)N_NODES * 4);              // 400 KB
    int*           bsum     = (int*)          carve((size_t)NBLK * 4);                 // ~1.6 KB
    unsigned char* partialR = (unsigned char*)carve((size_t)HB * N_NODES);             // 12.8 MB
    unsigned char* partialC = (unsigned char*)carve((size_t)HB * N_NODES);             // 12.8 MB
    int*           csc_row  = (int*)          carve((size_t)CSC_CAP * 4);              // 12.4 MB
    _Float16*      s0h      = (_Float16*)     carve((size_t)(N_NODES + 1) * N_PROBES * 2); // 6.4 MB
    unsigned int*  bufA8    = (unsigned int*) carve((size_t)(N_NODES + 1) * 32);       // 3.2 MB
    unsigned int*  bufB8    = (unsigned int*) carve((size_t)(N_NODES + 1) * 32);       // 3.2 MB
    float*         diags    = (float*)        carve((size_t)WALK_LEN * N_NODES * 4);   // 6.4 MB
    unsigned int*  pbits    = (unsigned int*) carve((size_t)N_NODES * 4);              // 400 KB

    const int B = 256;
    // ---- build CSC + inv_outdeg: fused hists (256 blocks), fused reduces ----
    hist2_kernel<<<2 * HB, 1024, 0, stream>>>(row, col, partialR, partialC);
    reduce2_kernel<<<2 * RB, B, 0, stream>>>(partialR, inv_od, partialC, indeg);
    scan1_kernel<<<NBLK, SCAN_BLK, 0, stream>>>(indeg, bsum);
    scan2_kernel<<<1, 512, 0, stream>>>(bsum);
    scan3_kernel<<<NBLK, SCAN_BLK, 0, stream>>>(indeg, bsum, offs);
    fill_dummy_kernel<<<(CSC_CAP / 4 + B - 1) / B, B, 0, stream>>>(csc_row);
    place_kernel<<<HB, 1024, 0, stream>>>(row, col, offs, partialC, csc_row);

    // ---- fused s0 (fp16) + probe-sign pack + dummy-row zero ----
    s0pack_kernel<<<(N_NODES * 8 + B - 1) / B, B, 0, stream>>>(probes, inv_od, s0h,
                                                               pbits, bufA8, bufB8);

    // ---- 16 fused transition + diag steps: step 0 fp16->fp8, steps 1..15 fp8->fp8 ----
    const int GRID = (N_NODES * 8 + B - 1) / B;
    gather_kernel<false><<<GRID, B, 0, stream>>>(offs, indeg, csc_row, (const void*)s0h,
                                                 pbits, inv_od, bufA8, diags);
    const unsigned int* cur = bufA8;
    for (int k = 1; k < WALK_LEN; k++) {
        unsigned int* nxt = (k & 1) ? bufB8 : bufA8;
        gather_kernel<true><<<GRID, B, 0, stream>>>(offs, indeg, csc_row, (const void*)cur,
                                                    pbits, inv_od, nxt, diags + (size_t)k * N_NODES);
        cur = nxt;
    }

    out_kernel<<<(N_NODES + B - 1) / B, B, 0, stream>>>(diags, W, b, out);
}

// Round 7
// 385.864 us; speedup vs baseline: 2.4267x; 2.4267x over previous
//
#include <hip/hip_runtime.h>

#define N_NODES   100000
#define N_EDGES   1600000
#define WALK_LEN  16
#define OUT_DIM   8
#define N_PROBES  32

#define SCAN_BLK  256
#define NBLK      ((N_NODES + SCAN_BLK - 1) / SCAN_BLK)   // 391

// ---- LDS byte-counter build parameters ----
#define HB        128                      // histogram blocks per array (row/col)
#define SLICE     (N_EDGES / HB)           // 12500 edges per block (exact)
#define NWORDS    (N_NODES / 4)            // 25000 packed uints = 100 KB LDS
#define RB        ((NWORDS + 255) / 256)   // reduce blocks per half

// ---- adjacency padding: every list rounded up to multiple of 16 (burst) ----
#define BURST     16
#define DUMMY     N_NODES                  // dummy source row (always zero)
#define CSC_CAP   (N_EDGES + (BURST - 1) * N_NODES)   // 3.1M padded entries

typedef _Float16 half4 __attribute__((ext_vector_type(4)));
typedef float float2v __attribute__((ext_vector_type(2)));

__device__ __forceinline__ int pad_burst(int x) { return (x + BURST - 1) & ~(BURST - 1); }

// ---------------- fused per-block byte-packed histograms: row -> partialR, col -> partialC ----
__global__ void hist2_kernel(const int* __restrict__ row, const int* __restrict__ col,
                             unsigned char* __restrict__ partialR,
                             unsigned char* __restrict__ partialC) {
    __shared__ unsigned int cnt[NWORDS];
    int blk = blockIdx.x;
    const int* arr = (blk < HB) ? row : col;
    unsigned char* partial = (blk < HB) ? partialR : partialC;
    int b = (blk < HB) ? blk : blk - HB;
    int t = threadIdx.x;                   // 1024 threads
    for (int i = t; i < NWORDS; i += 1024) cnt[i] = 0;
    __syncthreads();
    const int* a = arr + b * SLICE;
    for (int i = t; i < SLICE; i += 1024) {
        int v = a[i];
        atomicAdd(&cnt[v >> 2], 1u << ((v & 3) * 8));
    }
    __syncthreads();
    unsigned int* dst = (unsigned int*)(partial + (size_t)b * N_NODES);
    for (int i = t; i < NWORDS; i += 1024) dst[i] = cnt[i];
}

// ---------------- fused reduces: half A: outdeg->inv; half B: indeg + in-place prefix ----
__global__ void reduce2_kernel(const unsigned char* __restrict__ partialR,
                               float* __restrict__ inv_outdeg,
                               unsigned char* __restrict__ partialC,
                               int* __restrict__ indeg) {
    int blk = blockIdx.x;
    if (blk < RB) {
        int q = blk * 256 + threadIdx.x;
        if (q >= NWORDS) return;
        int s0 = 0, s1 = 0, s2 = 0, s3 = 0;
        for (int b = 0; b < HB; b++) {
            unsigned int w = *(const unsigned int*)(partialR + (size_t)b * N_NODES + q * 4);
            s0 += w & 0xFF; s1 += (w >> 8) & 0xFF; s2 += (w >> 16) & 0xFF; s3 += (w >> 24) & 0xFF;
        }
        int n = q * 4;
        inv_outdeg[n + 0] = 1.0f / (float)(s0 > 0 ? s0 : 1);
        inv_outdeg[n + 1] = 1.0f / (float)(s1 > 0 ? s1 : 1);
        inv_outdeg[n + 2] = 1.0f / (float)(s2 > 0 ? s2 : 1);
        inv_outdeg[n + 3] = 1.0f / (float)(s3 > 0 ? s3 : 1);
    } else {
        int q = (blk - RB) * 256 + threadIdx.x;
        if (q >= NWORDS) return;
        unsigned int r0 = 0, r1 = 0, r2 = 0, r3 = 0;     // running prefixes (fit in a byte)
        for (int b = 0; b < HB; b++) {
            unsigned int* p = (unsigned int*)(partialC + (size_t)b * N_NODES + q * 4);
            unsigned int w = *p;
            *p = (r0 & 0xFF) | ((r1 & 0xFF) << 8) | ((r2 & 0xFF) << 16) | ((r3 & 0xFF) << 24);
            r0 += w & 0xFF; r1 += (w >> 8) & 0xFF; r2 += (w >> 16) & 0xFF; r3 += (w >> 24) & 0xFF;
        }
        int n = q * 4;
        indeg[n + 0] = (int)r0;
        indeg[n + 1] = (int)r1;
        indeg[n + 2] = (int)r2;
        indeg[n + 3] = (int)r3;
    }
}

// ---------------- prefix scan of PADDED indeg -> offs (exclusive) ----------------
__global__ void scan1_kernel(const int* __restrict__ indeg, int* __restrict__ bsum) {
    __shared__ int s[SCAN_BLK];
    int i = blockIdx.x * SCAN_BLK + threadIdx.x;
    s[threadIdx.x] = (i < N_NODES) ? pad_burst(indeg[i]) : 0;
    __syncthreads();
    for (int o = SCAN_BLK / 2; o > 0; o >>= 1) {
        if (threadIdx.x < o) s[threadIdx.x] += s[threadIdx.x + o];
        __syncthreads();
    }
    if (threadIdx.x == 0) bsum[blockIdx.x] = s[0];
}

__global__ void scan2_kernel(int* __restrict__ bsum) {   // single block of 512
    __shared__ int s[512];
    int t = threadIdx.x;
    s[t] = (t < NBLK) ? bsum[t] : 0;
    __syncthreads();
    for (int o = 1; o < 512; o <<= 1) {
        int v = (t >= o) ? s[t - o] : 0;
        __syncthreads();
        s[t] += v;
        __syncthreads();
    }
    if (t < NBLK) bsum[t] = (t == 0) ? 0 : s[t - 1];     // exclusive
}

__global__ void scan3_kernel(const int* __restrict__ indeg, const int* __restrict__ bsum,
                             int* __restrict__ offs) {
    __shared__ int s[SCAN_BLK];
    int t = threadIdx.x;
    int i = blockIdx.x * SCAN_BLK + t;
    int v = (i < N_NODES) ? pad_burst(indeg[i]) : 0;
    s[t] = v;
    __syncthreads();
    for (int o = 1; o < SCAN_BLK; o <<= 1) {
        int u = (t >= o) ? s[t - o] : 0;
        __syncthreads();
        s[t] += u;
        __syncthreads();
    }
    if (i < N_NODES) offs[i] = bsum[blockIdx.x] + s[t] - v;   // exclusive
}

// ---------------- fill csc_row with DUMMY (pad slots resolve to zero row) ----------------
__global__ void fill_dummy_kernel(int* __restrict__ csc_row) {
    int i = blockIdx.x * blockDim.x + threadIdx.x;   // [0, CSC_CAP/4)
    if (i >= CSC_CAP / 4) return;
    reinterpret_cast<int4*>(csc_row)[i] = make_int4(DUMMY, DUMMY, DUMMY, DUMMY);
}

// ---------------- CSC fill: LDS byte rank counters seeded with prefix base ----------------
__global__ void place_kernel(const int* __restrict__ row, const int* __restrict__ col,
                             const int* __restrict__ offs,
                             const unsigned char* __restrict__ pbase,
                             int* __restrict__ csc_row) {
    __shared__ unsigned int cnt[NWORDS];
    int b = blockIdx.x;
    int t = threadIdx.x;                   // 1024 threads
    const unsigned int* src = (const unsigned int*)(pbase + (size_t)b * N_NODES);
    for (int i = t; i < NWORDS; i += 1024) cnt[i] = src[i];   // seed with prefix-base bytes
    __syncthreads();
    for (int i = t; i < SLICE; i += 1024) {
        int e = b * SLICE + i;
        int c = col[e];
        int sh = (c & 3) * 8;
        unsigned int old = atomicAdd(&cnt[c >> 2], 1u << sh);
        int pos = (int)((old >> sh) & 0xFF);               // prefix-base + in-block rank
        csc_row[offs[c] + pos] = row[e];
    }
}

// ---------------- fused: s0 = fp16(probes*inv_od), probe-sign pack, dummy-row zero ----------
__global__ void s0pack_kernel(const float* __restrict__ probes, const float* __restrict__ inv_outdeg,
                              _Float16* __restrict__ s0h, unsigned int* __restrict__ pbits,
                              unsigned int* __restrict__ a8, unsigned int* __restrict__ b8) {
    int gid = blockIdx.x * blockDim.x + threadIdx.x;   // [0, N*8)
    if (gid < 16)      reinterpret_cast<unsigned int*>(s0h + (size_t)DUMMY * N_PROBES)[gid] = 0u;
    else if (gid < 24) a8[(size_t)DUMMY * 8 + (gid - 16)] = 0u;
    else if (gid < 32) b8[(size_t)DUMMY * 8 + (gid - 24)] = 0u;
    int n = gid >> 3;
    int j = (gid & 7) << 2;
    float iv = inv_outdeg[n];
    const float4 p = *reinterpret_cast<const float4*>(probes + (size_t)n * N_PROBES + j);
    half4 h;
    h[0] = (_Float16)(p.x * iv); h[1] = (_Float16)(p.y * iv);
    h[2] = (_Float16)(p.z * iv); h[3] = (_Float16)(p.w * iv);
    *reinterpret_cast<half4*>(s0h + (size_t)n * N_PROBES + j) = h;
    unsigned int b4 = (p.x < 0.f ? 1u : 0u) | (p.y < 0.f ? 2u : 0u) |
                      (p.z < 0.f ? 4u : 0u) | (p.w < 0.f ? 8u : 0u);
    unsigned int bits = b4 << j;
    bits |= __shfl_xor(bits, 1, 8);
    bits |= __shfl_xor(bits, 2, 8);
    bits |= __shfl_xor(bits, 4, 8);
    if ((gid & 7) == 0) pbits[n] = bits;
}

// ---------------- fused gather + rescale + Hutchinson diag ----------------
// State rows: 32 probes. IN8=false: fp16 rows (64B, lane reads 8B half4) — step 0 only.
// IN8=true: fp8 e4m3 rows (32B, lane reads 4B dword, HW cvt_pk_f32_fp8 unpack).
// Output always fp8. fp32 accumulation. Padded burst-16 + one-burst-ahead index prefetch.
// NO __launch_bounds__ (R5 lesson: capping below the ~90-VGPR pipeline live set spills
// the whole burst pipeline to scratch, 3x regression). Index loads are PLAIN (L1-cached):
// 16 consecutive 4B loads/lane share 1-2 64B lines -> 1 miss + 15 L1 hits; NT bypassed L1
// and made every index load an L2-class request (R5 lesson #2).
template <bool IN8>
__global__ void gather_kernel(const int* __restrict__ offs, const int* __restrict__ indeg,
                              const int* __restrict__ csc_row,
                              const void* __restrict__ s_cur,
                              const unsigned int* __restrict__ pbits,
                              const float* __restrict__ inv_outdeg,
                              unsigned int* __restrict__ s_new, float* __restrict__ diag_row) {
    int gid = blockIdx.x * blockDim.x + threadIdx.x;   // [0, N*8) exact
    int n = gid >> 3;
    int lane = gid & 7;
    int start = offs[n];
    int pcnt  = pad_burst(indeg[n]);                   // multiple of BURST
    float inv = inv_outdeg[n];
    float4 acc = make_float4(0.f, 0.f, 0.f, 0.f);

    const _Float16*     h_base = (const _Float16*)s_cur;
    const unsigned int* q_base = (const unsigned int*)s_cur;

    int r[BURST];
    if (pcnt > 0) {
#pragma unroll
        for (int u = 0; u < BURST; u++) r[u] = csc_row[start + u];
    }
    for (int q = 0; q < pcnt; q += BURST) {
        // issue BURST independent state loads
        half4        vh[BURST];
        unsigned int vq[BURST];
#pragma unroll
        for (int u = 0; u < BURST; u++) {
            if (IN8) vq[u] = q_base[(size_t)r[u] * 8 + lane];
            else     vh[u] = *reinterpret_cast<const half4*>(h_base + (size_t)r[u] * N_PROBES + lane * 4);
        }
        // prefetch next burst's indices while state loads are in flight
        int r2[BURST];
        if (q + BURST < pcnt) {
#pragma unroll
            for (int u = 0; u < BURST; u++) r2[u] = csc_row[start + q + BURST + u];
        }
#pragma unroll
        for (int u = 0; u < BURST; u++) {
            if (IN8) {
                float2v lo = __builtin_amdgcn_cvt_pk_f32_fp8((int)vq[u], false);
                float2v hi = __builtin_amdgcn_cvt_pk_f32_fp8((int)vq[u], true);
                acc.x += lo[0]; acc.y += lo[1]; acc.z += hi[0]; acc.w += hi[1];
            } else {
                acc.x += (float)vh[u][0]; acc.y += (float)vh[u][1];
                acc.z += (float)vh[u][2]; acc.w += (float)vh[u][3];
            }
        }
#pragma unroll
        for (int u = 0; u < BURST; u++) r[u] = r2[u];
    }

    // acc = P_k[n] fragment (fp32). Write pre-scaled fp8 row for next step.
    int pk = 0;
    pk = __builtin_amdgcn_cvt_pk_fp8_f32(acc.x * inv, acc.y * inv, pk, false);
    pk = __builtin_amdgcn_cvt_pk_fp8_f32(acc.z * inv, acc.w * inv, pk, true);
    s_new[(size_t)n * 8 + lane] = (unsigned int)pk;

    // Hutchinson dot via packed probe signs (probes are exactly ±1)
    unsigned int bits = pbits[n] >> (lane << 2);
    float d0 = (bits & 1u) ? -acc.x : acc.x;
    float d1 = (bits & 2u) ? -acc.y : acc.y;
    float d2 = (bits & 4u) ? -acc.z : acc.z;
    float d3 = (bits & 8u) ? -acc.w : acc.w;
    float dot = d0 + d1 + d2 + d3;
    dot += __shfl_xor(dot, 4, 8);
    dot += __shfl_xor(dot, 2, 8);
    dot += __shfl_xor(dot, 1, 8);
    if (lane == 0) diag_row[n] = dot * (1.0f / (float)N_PROBES);
}

// ---------------- out[n] = diags[n,:] @ W^T + b ----------------
__global__ void out_kernel(const float* __restrict__ diags, const float* __restrict__ W,
                           const float* __restrict__ b, float* __restrict__ out) {
    int n = blockIdx.x * blockDim.x + threadIdx.x;
    if (n >= N_NODES) return;
    float d[WALK_LEN];
#pragma unroll
    for (int k = 0; k < WALK_LEN; k++) d[k] = diags[(size_t)k * N_NODES + n];
    float o[OUT_DIM];
#pragma unroll
    for (int j = 0; j < OUT_DIM; j++) {
        float acc = b[j];
#pragma unroll
        for (int k = 0; k < WALK_LEN; k++) acc += d[k] * W[j * WALK_LEN + k];
        o[j] = acc;
    }
    float4* outp = reinterpret_cast<float4*>(out + (size_t)n * OUT_DIM);
    outp[0] = make_float4(o[0], o[1], o[2], o[3]);
    outp[1] = make_float4(o[4], o[5], o[6], o[7]);
}

extern "C" void kernel_launch(void* const* d_in, const int* in_sizes, int n_in,
                              void* d_out, int out_size, void* d_ws, size_t ws_size,
                              hipStream_t stream) {
    const int*   edge_index = (const int*)d_in[0];
    const int*   row    = edge_index;
    const int*   col    = edge_index + N_EDGES;
    const float* probes = (const float*)d_in[2];
    const float* W      = (const float*)d_in[3];
    const float* b      = (const float*)d_in[4];
    float*       out    = (float*)d_out;

    // workspace carve-up (256B aligned)
    char* ws = (char*)d_ws;
    size_t off = 0;
    auto carve = [&](size_t bytes) -> void* {
        void* p = ws + off;
        off += (bytes + 255) & ~(size_t)255;
        return p;
    };
    int*           indeg    = (int*)          carve((size_t)N_NODES * 4);              // 400 KB
    int*           offs     = (int*)          carve((size_t)N_NODES * 4);              // 400 KB
    float*         inv_od   = (float*)        carve((size_t)N_NODES * 4);              // 400 KB
    int*           bsum     = (int*)          carve((size_t)NBLK * 4);                 // ~1.6 KB
    unsigned char* partialR = (unsigned char*)carve((size_t)HB * N_NODES);             // 12.8 MB
    unsigned char* partialC = (unsigned char*)carve((size_t)HB * N_NODES);             // 12.8 MB
    int*           csc_row  = (int*)          carve((size_t)CSC_CAP * 4);              // 12.4 MB
    _Float16*      s0h      = (_Float16*)     carve((size_t)(N_NODES + 1) * N_PROBES * 2); // 6.4 MB
    unsigned int*  bufA8    = (unsigned int*) carve((size_t)(N_NODES + 1) * 32);       // 3.2 MB
    unsigned int*  bufB8    = (unsigned int*) carve((size_t)(N_NODES + 1) * 32);       // 3.2 MB
    float*         diags    = (float*)        carve((size_t)WALK_LEN * N_NODES * 4);   // 6.4 MB
    unsigned int*  pbits    = (unsigned int*) carve((size_t)N_NODES * 4);              // 400 KB

    const int B = 256;
    // ---- build CSC + inv_outdeg: fused hists (256 blocks), fused reduces ----
    hist2_kernel<<<2 * HB, 1024, 0, stream>>>(row, col, partialR, partialC);
    reduce2_kernel<<<2 * RB, B, 0, stream>>>(partialR, inv_od, partialC, indeg);
    scan1_kernel<<<NBLK, SCAN_BLK, 0, stream>>>(indeg, bsum);
    scan2_kernel<<<1, 512, 0, stream>>>(bsum);
    scan3_kernel<<<NBLK, SCAN_BLK, 0, stream>>>(indeg, bsum, offs);
    fill_dummy_kernel<<<(CSC_CAP / 4 + B - 1) / B, B, 0, stream>>>(csc_row);
    place_kernel<<<HB, 1024, 0, stream>>>(row, col, offs, partialC, csc_row);

    // ---- fused s0 (fp16) + probe-sign pack + dummy-row zero ----
    s0pack_kernel<<<(N_NODES * 8 + B - 1) / B, B, 0, stream>>>(probes, inv_od, s0h,
                                                               pbits, bufA8, bufB8);

    // ---- 16 fused transition + diag steps: step 0 fp16->fp8, steps 1..15 fp8->fp8 ----
    const int GRID = (N_NODES * 8 + B - 1) / B;
    gather_kernel<false><<<GRID, B, 0, stream>>>(offs, indeg, csc_row, (const void*)s0h,
                                                 pbits, inv_od, bufA8, diags);
    const unsigned int* cur = bufA8;
    for (int k = 1; k < WALK_LEN; k++) {
        unsigned int* nxt = (k & 1) ? bufB8 : bufA8;
        gather_kernel<true><<<GRID, B, 0, stream>>>(offs, indeg, csc_row, (const void*)cur,
                                                    pbits, inv_od, nxt, diags + (size_t)k * N_NODES);
        cur = nxt;
    }

    out_kernel<<<(N_NODES + B - 1) / B, B, 0, stream>>>(diags, W, b, out);
}